// Round 1
// baseline (683.787 us; speedup 1.0000x reference)
//
#include <hip/hip_runtime.h>
#include <hip/hip_bf16.h>
#include <stdint.h>

#define VOCAB 100000
#define HID 128
#define BATCH 1024

typedef __attribute__((ext_vector_type(8))) short short8;
typedef __attribute__((ext_vector_type(4))) float float4v;
typedef __attribute__((ext_vector_type(16))) float float16v;

__device__ __forceinline__ unsigned short f2bf_rne(float f) {
    union { float f; uint32_t u; } v; v.f = f;
    uint32_t u = v.u;
    u += 0x7fffu + ((u >> 16) & 1u);   // round-to-nearest-even on bf16 boundary
    return (unsigned short)(u >> 16);
}

// ---------------------------------------------------------------------------
// Kernel 1: GRU cell. 4 batch rows per block, 256 threads.
// Thread t -> unit u = t>>1 (0..127), k-half kh = t&1 (64 k each).
// gh dot products in fp32 (W_hh is 196 KB -> L2-resident); gi is a scattered
// gather from W_ih columns, issued first to overlap HBM latency.
// ---------------------------------------------------------------------------
__global__ __launch_bounds__(256) void gru_kernel(
    const int* __restrict__ idx,
    const float* __restrict__ h0,
    const float* __restrict__ W_ih,
    const float* __restrict__ b_ih,
    const float* __restrict__ W_hh,
    const float* __restrict__ b_hh,
    float* __restrict__ h_out,          // d_out + BATCH*VOCAB (fp32)
    unsigned short* __restrict__ h_bf)  // d_ws (bf16 copy for GEMM A)
{
    const int t  = threadIdx.x;
    const int u  = t >> 1;     // hidden unit
    const int kh = t & 1;      // which half of k
    const int b0 = blockIdx.x * 4;

    __shared__ float hs[4][HID];
    for (int r = t >> 7; r < 4; r += 2)
        hs[r][t & 127] = h0[(size_t)(b0 + r) * HID + (t & 127)];

    // gather gi for my 2 rows (even lanes: rows 0,1; odd lanes: rows 2,3)
    float gi[2][3];
    #pragma unroll
    for (int i = 0; i < 2; ++i) {
        int b  = b0 + kh * 2 + i;
        int ix = idx[b];
        #pragma unroll
        for (int g = 0; g < 3; ++g)
            gi[i][g] = W_ih[(size_t)(g * HID + u) * VOCAB + ix] + b_ih[g * HID + u];
    }

    __syncthreads();

    float acc[4][3];
    #pragma unroll
    for (int r = 0; r < 4; ++r)
        #pragma unroll
        for (int g = 0; g < 3; ++g)
            acc[r][g] = 0.f;

    const int kbase = kh * 64;
    #pragma unroll 4
    for (int i = 0; i < 16; ++i) {
        int k = kbase + i * 4;
        float4v w[3];
        #pragma unroll
        for (int g = 0; g < 3; ++g)
            w[g] = *(const float4v*)&W_hh[(size_t)(g * HID + u) * HID + k];
        #pragma unroll
        for (int r = 0; r < 4; ++r) {
            float4v h = *(const float4v*)&hs[r][k];
            #pragma unroll
            for (int g = 0; g < 3; ++g)
                acc[r][g] += w[g][0]*h[0] + w[g][1]*h[1] + w[g][2]*h[2] + w[g][3]*h[3];
        }
    }

    // combine the two k-halves (lanes t and t^1 hold the same (u) pair)
    #pragma unroll
    for (int r = 0; r < 4; ++r)
        #pragma unroll
        for (int g = 0; g < 3; ++g)
            acc[r][g] += __shfl_xor(acc[r][g], 1, 64);

    const float bh_r = b_hh[u];
    const float bh_z = b_hh[HID + u];
    const float bh_n = b_hh[2 * HID + u];

    #pragma unroll
    for (int i = 0; i < 2; ++i) {
        int r = kh * 2 + i;           // my row (matches gi[i])
        float gh_r = acc[r][0] + bh_r;
        float gh_z = acc[r][1] + bh_z;
        float gh_n = acc[r][2] + bh_n;
        float rr = 1.f / (1.f + expf(-(gi[i][0] + gh_r)));
        float zz = 1.f / (1.f + expf(-(gi[i][1] + gh_z)));
        float nn = tanhf(gi[i][2] + rr * gh_n);
        float hp = hs[r][u];
        float hn = (1.f - zz) * nn + zz * hp;
        size_t o = (size_t)(b0 + r) * HID + u;
        h_out[o] = hn;
        h_bf[o]  = f2bf_rne(hn);
    }
}

// ---------------------------------------------------------------------------
// Kernel 2: logits = ReLU(h_new @ W_out^T + b_out) via bf16 MFMA 32x32x16.
// Block = 256 threads (4 waves). Tile: M=64, N=128 (wave w owns n-strip w*32).
// K=128 fully unrolled (8 MFMA steps, 2 m-frags each). W_out converted
// fp32->bf16 on the fly. Grid: x = 16 m-tiles (fastest -> L2 reuse of W_out),
// y = 782 n-tiles (last one ragged: 100000 = 781*128 + 32).
// ---------------------------------------------------------------------------
__global__ __launch_bounds__(256) void out_gemm_kernel(
    const unsigned short* __restrict__ A,  // h_new bf16 (BATCH x HID)
    const float* __restrict__ W,           // W_out (VOCAB x HID) fp32
    const float* __restrict__ bias,        // b_out (VOCAB)
    float* __restrict__ out)               // logits (BATCH x VOCAB)
{
    const int lane = threadIdx.x & 63;
    const int wave = threadIdx.x >> 6;
    const int m0   = blockIdx.x * 64;
    const int n0   = blockIdx.y * 128 + wave * 32;

    const int l31 = lane & 31;
    const int lhi = lane >> 5;   // 0/1

    const int v  = n0 + l31;
    const int vc = v < VOCAB ? v : (VOCAB - 1);

    float16v acc0, acc1;
    #pragma unroll
    for (int i = 0; i < 16; ++i) { acc0[i] = 0.f; acc1[i] = 0.f; }

    const unsigned short* Ap0 = A + (size_t)(m0 + l31) * HID + lhi * 8;
    const unsigned short* Ap1 = Ap0 + 32 * HID;
    const float*          Wp  = W + (size_t)vc * HID + lhi * 8;

    #pragma unroll
    for (int kk = 0; kk < 8; ++kk) {
        const int k = kk * 16;
        short8 a0 = *(const short8*)(Ap0 + k);
        short8 a1 = *(const short8*)(Ap1 + k);
        float4v w0 = *(const float4v*)(Wp + k);
        float4v w1 = *(const float4v*)(Wp + k + 4);
        short8 b;
        #pragma unroll
        for (int j = 0; j < 4; ++j) {
            b[j]     = (short)f2bf_rne(w0[j]);
            b[j + 4] = (short)f2bf_rne(w1[j]);
        }
        acc0 = __builtin_amdgcn_mfma_f32_32x32x16_bf16(a0, b, acc0, 0, 0, 0);
        acc1 = __builtin_amdgcn_mfma_f32_32x32x16_bf16(a1, b, acc1, 0, 0, 0);
    }

    if (v < VOCAB) {
        const float bv = bias[vc];
        float* outb = out + (size_t)m0 * VOCAB + v;
        #pragma unroll
        for (int r = 0; r < 16; ++r) {
            int mrow = (r & 3) + 8 * (r >> 2) + 4 * lhi;  // verified C/D mapping
            float v0 = acc0[r] + bv; v0 = v0 > 0.f ? v0 : 0.f;
            float v1 = acc1[r] + bv; v1 = v1 > 0.f ? v1 : 0.f;
            outb[(size_t)mrow * VOCAB]        = v0;
            outb[(size_t)(mrow + 32) * VOCAB] = v1;
        }
    }
}

extern "C" void kernel_launch(void* const* d_in, const int* in_sizes, int n_in,
                              void* d_out, int out_size, void* d_ws, size_t ws_size,
                              hipStream_t stream) {
    const int*   idx   = (const int*)d_in[0];
    const float* h0    = (const float*)d_in[1];
    const float* W_ih  = (const float*)d_in[2];
    const float* b_ih  = (const float*)d_in[3];
    const float* W_hh  = (const float*)d_in[4];
    const float* b_hh  = (const float*)d_in[5];
    const float* W_out = (const float*)d_in[6];
    const float* b_out = (const float*)d_in[7];

    float* out = (float*)d_out;
    unsigned short* hbf = (unsigned short*)d_ws;   // 256 KB bf16 h_new

    gru_kernel<<<BATCH / 4, 256, 0, stream>>>(
        idx, h0, W_ih, b_ih, W_hh, b_hh,
        out + (size_t)BATCH * VOCAB, hbf);

    dim3 grid(BATCH / 64, (VOCAB + 127) / 128);
    out_gemm_kernel<<<grid, 256, 0, stream>>>(hbf, W_out, b_out, out);
}

// Round 2
// 624.464 us; speedup vs baseline: 1.0950x; 1.0950x over previous
//
#include <hip/hip_runtime.h>
#include <hip/hip_bf16.h>
#include <stdint.h>

#define VOCAB 100000
#define HID 128
#define BATCH 1024

#define W_ELTS (VOCAB * HID)          // 12,800,000
#define CONV_BLOCKS (W_ELTS / 2048)   // 6250 blocks, 8 elts/thread, 256 thr
#define GRU_BLOCKS (BATCH / 4)        // 256

typedef __attribute__((ext_vector_type(8))) short short8;
typedef __attribute__((ext_vector_type(4))) float float4v;
typedef __attribute__((ext_vector_type(16))) float float16v;

__device__ __forceinline__ unsigned short f2bf_rne(float f) {
    union { float f; uint32_t u; } v; v.f = f;
    uint32_t u = v.u;
    u += 0x7fffu + ((u >> 16) & 1u);   // round-to-nearest-even on bf16 boundary
    return (unsigned short)(u >> 16);
}

// ---------------------------------------------------------------------------
// Kernel 1 (fused prep):
//   blocks [0, GRU_BLOCKS)            : GRU cell, 4 batch rows/block
//   blocks [GRU_BLOCKS, +CONV_BLOCKS) : W_out fp32 -> bf16 streaming convert
// GRU blocks dispatch first so their scattered W_ih gathers (HBM latency)
// overlap the bandwidth-bound convert.
// ---------------------------------------------------------------------------
__global__ __launch_bounds__(256) void prep_kernel(
    const int* __restrict__ idx,
    const float* __restrict__ h0,
    const float* __restrict__ W_ih,
    const float* __restrict__ b_ih,
    const float* __restrict__ W_hh,
    const float* __restrict__ b_hh,
    const float* __restrict__ W_out,
    float* __restrict__ h_out,            // d_out + BATCH*VOCAB (fp32)
    unsigned short* __restrict__ W_bf,    // d_ws[0 .. W_ELTS)
    unsigned short* __restrict__ h_bf)    // d_ws[W_ELTS ..)
{
    const int t = threadIdx.x;

    if (blockIdx.x >= GRU_BLOCKS) {
        // ---- W_out convert: 8 elements per thread, fully coalesced ----
        const size_t base = ((size_t)(blockIdx.x - GRU_BLOCKS) * 256 + t) * 8;
        float4v w0 = *(const float4v*)(W_out + base);
        float4v w1 = *(const float4v*)(W_out + base + 4);
        short8 b;
        #pragma unroll
        for (int j = 0; j < 4; ++j) {
            b[j]     = (short)f2bf_rne(w0[j]);
            b[j + 4] = (short)f2bf_rne(w1[j]);
        }
        *(short8*)(W_bf + base) = b;
        return;
    }

    // ---- GRU: thread t -> unit u = t>>1, k-half kh = t&1 ----
    const int u  = t >> 1;
    const int kh = t & 1;
    const int b0 = blockIdx.x * 4;

    __shared__ float hs[4][HID];
    for (int r = t >> 7; r < 4; r += 2)
        hs[r][t & 127] = h0[(size_t)(b0 + r) * HID + (t & 127)];

    // scattered gi gather (even lanes: rows 0,1; odd lanes: rows 2,3)
    float gi[2][3];
    #pragma unroll
    for (int i = 0; i < 2; ++i) {
        int b  = b0 + kh * 2 + i;
        int ix = idx[b];
        #pragma unroll
        for (int g = 0; g < 3; ++g)
            gi[i][g] = W_ih[(size_t)(g * HID + u) * VOCAB + ix] + b_ih[g * HID + u];
    }

    __syncthreads();

    float acc[4][3];
    #pragma unroll
    for (int r = 0; r < 4; ++r)
        #pragma unroll
        for (int g = 0; g < 3; ++g)
            acc[r][g] = 0.f;

    const int kbase = kh * 64;
    #pragma unroll 4
    for (int i = 0; i < 16; ++i) {
        int k = kbase + i * 4;
        float4v w[3];
        #pragma unroll
        for (int g = 0; g < 3; ++g)
            w[g] = *(const float4v*)&W_hh[(size_t)(g * HID + u) * HID + k];
        #pragma unroll
        for (int r = 0; r < 4; ++r) {
            float4v h = *(const float4v*)&hs[r][k];
            #pragma unroll
            for (int g = 0; g < 3; ++g)
                acc[r][g] += w[g][0]*h[0] + w[g][1]*h[1] + w[g][2]*h[2] + w[g][3]*h[3];
        }
    }

    #pragma unroll
    for (int r = 0; r < 4; ++r)
        #pragma unroll
        for (int g = 0; g < 3; ++g)
            acc[r][g] += __shfl_xor(acc[r][g], 1, 64);

    const float bh_r = b_hh[u];
    const float bh_z = b_hh[HID + u];
    const float bh_n = b_hh[2 * HID + u];

    #pragma unroll
    for (int i = 0; i < 2; ++i) {
        int r = kh * 2 + i;
        float gh_r = acc[r][0] + bh_r;
        float gh_z = acc[r][1] + bh_z;
        float gh_n = acc[r][2] + bh_n;
        float rr = 1.f / (1.f + expf(-(gi[i][0] + gh_r)));
        float zz = 1.f / (1.f + expf(-(gi[i][1] + gh_z)));
        float nn = tanhf(gi[i][2] + rr * gh_n);
        float hp = hs[r][u];
        float hn = (1.f - zz) * nn + zz * hp;
        size_t o = (size_t)(b0 + r) * HID + u;
        h_out[o] = hn;
        h_bf[o]  = f2bf_rne(hn);
    }
}

// ---------------------------------------------------------------------------
// Kernel 2: logits = ReLU(h_new @ W_out^T + b_out), all-bf16 inputs via
// MFMA 32x32x16. Block = 4 waves; tile M=64 x N=128 (wave w -> n-strip w*32).
// K=128 fully unrolled: per step 3 x 16B loads + 2 MFMA, zero conversion VALU.
// Grid x = 16 m-tiles (fastest -> L2 reuse of the W n-strip), y = 782 n-tiles.
// Logit stores are nontemporal (never re-read; keep them out of L2).
// ---------------------------------------------------------------------------
__global__ __launch_bounds__(256) void out_gemm_kernel(
    const unsigned short* __restrict__ A,   // h_new bf16 (BATCH x HID)
    const unsigned short* __restrict__ Wb,  // W_out bf16 (VOCAB x HID)
    const float* __restrict__ bias,         // b_out (VOCAB)
    float* __restrict__ out)                // logits (BATCH x VOCAB)
{
    const int lane = threadIdx.x & 63;
    const int wave = threadIdx.x >> 6;
    const int m0   = blockIdx.x * 64;
    const int n0   = blockIdx.y * 128 + wave * 32;

    const int l31 = lane & 31;
    const int lhi = lane >> 5;   // 0/1

    const int v  = n0 + l31;
    const int vc = v < VOCAB ? v : (VOCAB - 1);

    float16v acc0, acc1;
    #pragma unroll
    for (int i = 0; i < 16; ++i) { acc0[i] = 0.f; acc1[i] = 0.f; }

    const unsigned short* Ap0 = A + (size_t)(m0 + l31) * HID + lhi * 8;
    const unsigned short* Ap1 = Ap0 + 32 * HID;
    const unsigned short* Wp  = Wb + (size_t)vc * HID + lhi * 8;

    #pragma unroll
    for (int kk = 0; kk < 8; ++kk) {
        const int k = kk * 16;
        short8 a0 = *(const short8*)(Ap0 + k);
        short8 a1 = *(const short8*)(Ap1 + k);
        short8 b  = *(const short8*)(Wp + k);
        acc0 = __builtin_amdgcn_mfma_f32_32x32x16_bf16(a0, b, acc0, 0, 0, 0);
        acc1 = __builtin_amdgcn_mfma_f32_32x32x16_bf16(a1, b, acc1, 0, 0, 0);
    }

    if (v < VOCAB) {
        const float bv = bias[vc];
        float* outb = out + (size_t)m0 * VOCAB + v;
        #pragma unroll
        for (int r = 0; r < 16; ++r) {
            int mrow = (r & 3) + 8 * (r >> 2) + 4 * lhi;  // verified C/D mapping
            float v0 = acc0[r] + bv; v0 = v0 > 0.f ? v0 : 0.f;
            float v1 = acc1[r] + bv; v1 = v1 > 0.f ? v1 : 0.f;
            __builtin_nontemporal_store(v0, outb + (size_t)mrow * VOCAB);
            __builtin_nontemporal_store(v1, outb + (size_t)(mrow + 32) * VOCAB);
        }
    }
}

extern "C" void kernel_launch(void* const* d_in, const int* in_sizes, int n_in,
                              void* d_out, int out_size, void* d_ws, size_t ws_size,
                              hipStream_t stream) {
    const int*   idx   = (const int*)d_in[0];
    const float* h0    = (const float*)d_in[1];
    const float* W_ih  = (const float*)d_in[2];
    const float* b_ih  = (const float*)d_in[3];
    const float* W_hh  = (const float*)d_in[4];
    const float* b_hh  = (const float*)d_in[5];
    const float* W_out = (const float*)d_in[6];
    const float* b_out = (const float*)d_in[7];

    float* out = (float*)d_out;
    unsigned short* W_bf = (unsigned short*)d_ws;            // 25.6 MB
    unsigned short* h_bf = (unsigned short*)d_ws + W_ELTS;   // 256 KB

    prep_kernel<<<GRU_BLOCKS + CONV_BLOCKS, 256, 0, stream>>>(
        idx, h0, W_ih, b_ih, W_hh, b_hh, W_out,
        out + (size_t)BATCH * VOCAB, W_bf, h_bf);

    dim3 grid(BATCH / 64, (VOCAB + 127) / 128);
    out_gemm_kernel<<<grid, 256, 0, stream>>>(h_bf, W_bf, b_out, out);
}